// Round 5
// baseline (174.760 us; speedup 1.0000x reference)
//
#include <hip/hip_runtime.h>

typedef _Float16 f16;
typedef f16  f16x4 __attribute__((ext_vector_type(4)));
typedef f16  f16x8 __attribute__((ext_vector_type(8)));
typedef __fp16 h16x2 __attribute__((ext_vector_type(2)));  // cvt_pkrtz native return type
typedef float f32x4  __attribute__((ext_vector_type(4)));
typedef float f32x16 __attribute__((ext_vector_type(16)));
typedef unsigned int u32;
typedef u32 u32x2 __attribute__((ext_vector_type(2)));
typedef u32 u32x4 __attribute__((ext_vector_type(4)));

#define LOG2E   1.4426950408889634f
#define LN2     0.6931471805599453f
#define C_SIN   0.15915494309189535f   // 1/(2*pi)
#define C_SIG  -1.4426950408889634f    // -log2(e)
#define C_GSQ   0.84932181f            // sqrt(log2(e)/2): gauss = exp2(-(s*u)^2)

// per-node arg prescale baked into W,b at prep.
// acts 0=tanh(Pade,raw) 1=elu(raw) 2=softplus(raw) 3=sin(1/2pi) 4=gauss(sqrt bake) 5=sigmoid(0.5 bake)
__device__ __constant__ float NSCL[12] = {
    1.0f, 1.0f, 1.0f, 1.0f, C_SIN, C_GSQ, 0.5f, 1.0f, 1.0f, 1.0f, C_SIN, C_GSQ
};

__device__ __forceinline__ float frcp(float x){ return __builtin_amdgcn_rcpf(x); }
__device__ __forceinline__ float fexp2(float x){ return __builtin_amdgcn_exp2f(x); }
__device__ __forceinline__ float flog2(float x){ return __builtin_amdgcn_logf(x); }
__device__ __forceinline__ float fsin1(float x){ return __builtin_amdgcn_sinf(x); } // arg in revolutions
__device__ __forceinline__ float clamp46(float x){ return __builtin_amdgcn_fmed3f(x, -4.6f, 4.6f); }

// ---- Pade(7,6) tanh: exact to <2e-5 on [-4.6,4.6]; replaces exp2+rcp (2 trans)
// with ~10 plain-VALU ops + a SHARED rcp (batched 4- or 2-wide).
__device__ __forceinline__ float pnum(float x, float x2){
    float p = x2 + 378.0f;
    p = fmaf(x2, p, 17325.0f);
    p = fmaf(x2, p, 135135.0f);
    return x * p;
}
__device__ __forceinline__ float pden(float x2){
    float q = fmaf(x2, 28.0f, 3150.0f);
    q = fmaf(x2, q, 62370.0f);
    q = fmaf(x2, q, 135135.0f);
    return q;
}
// 4 tanh evals sharing ONE v_rcp (exact batched reciprocal; dens in [1.35e5,3.2e6]
// so the 4-product stays ~1e26 << f32 max). SIG: sigmoid(2v)=0.5+0.5*tanh(v).
template<bool SIG>
__device__ __forceinline__ void tanh4b(float v0, float v1, float v2, float v3, float* o){
    float x0 = clamp46(v0), x1 = clamp46(v1), x2 = clamp46(v2), x3 = clamp46(v3);
    float s0 = x0*x0, s1 = x1*x1, s2 = x2*x2, s3 = x3*x3;
    float n0 = pnum(x0,s0), n1 = pnum(x1,s1), n2 = pnum(x2,s2), n3 = pnum(x3,s3);
    float d0 = pden(s0),    d1 = pden(s1),    d2 = pden(s2),    d3 = pden(s3);
    float d01 = d0*d1, d23 = d2*d3;
    float rP  = frcp(d01*d23);
    float r01 = d23*rP, r23 = d01*rP;
    o[0] = n0*(d1*r01); o[1] = n1*(d0*r01);
    o[2] = n2*(d3*r23); o[3] = n3*(d2*r23);
    if constexpr (SIG){
        o[0] = fmaf(0.5f, o[0], 0.5f); o[1] = fmaf(0.5f, o[1], 0.5f);
        o[2] = fmaf(0.5f, o[2], 0.5f); o[3] = fmaf(0.5f, o[3], 0.5f);
    }
}

// ---------- scalar activations (non-tanh-family) on PRESCALED args ----------
template<int A> __device__ __forceinline__ float act(float v){
    if constexpr (A == 1){                       // elu; v raw
        float e = fexp2(v * LOG2E) - 1.0f;
        return v > 0.0f ? v : e;
    } else if constexpr (A == 2){                // softplus; v raw
        float p = fexp2(-LOG2E * fabsf(v));
        return fmaxf(v, 0.0f) + LN2 * flog2(1.0f + p);
    } else if constexpr (A == 3){                // sin; v = x/(2pi)
        return fsin1(v);
    } else {                                     // gauss; v = sqrt(log2e/2)*x
        return fexp2(-(v * v));
    }
}

__device__ __forceinline__ f16x4 pack4(float a, float b, float c, float d){
    u32x2 u;
    u[0] = __builtin_bit_cast(u32, __builtin_amdgcn_cvt_pkrtz(a, b));
    u[1] = __builtin_bit_cast(u32, __builtin_amdgcn_cvt_pkrtz(c, d));
    return __builtin_bit_cast(f16x4, u);
}
__device__ __forceinline__ f16x8 cat8(f16x4 lo, f16x4 hi){
    u32x2 a = __builtin_bit_cast(u32x2, lo), b = __builtin_bit_cast(u32x2, hi);
    u32x4 u; u[0] = a[0]; u[1] = a[1]; u[2] = b[0]; u[3] = b[1];
    return __builtin_bit_cast(f16x8, u);
}

#define MFMA32(a, b, c) __builtin_amdgcn_mfma_f32_32x32x16_f16((a), (b), (c), 0, 0, 0)

// K-permutation pi: k-slot (kc, 8h+j) holds feature 8*kc + 32*(j>>2) + 4*h + (j&3);
// next node's B-frag[kc] = cat(pk[t=0][g=kc], pk[t=1][g=kc]) -- registers only.
//
// SINGLE-tile node (one 32-pt tile per wave): 16-wave workgroup caps the unified
// register budget at 128/wave (64 arch VGPR + 64 AGPR with MFMA) -- dual-tile
// state spilled ~500MB/dispatch (rounds 1-2); single-tile fits with zero scratch.
template<int ACTI, int NP>
__device__ __forceinline__ void node32(const f16* __restrict__ wr,   // &wfrag[ni][0][0][lane][0]
                                       const float* __restrict__ bs, // &b_s[ni][0] (prescaled)
                                       const int hf4,                // 4*(lane>>5)
                                       const f16x8 A0[4], const f16x8 A1[4], const f16x8 A2[4],
                                       f16x8 OUT[4])
{
    f16x4 pk[2][4];
    #pragma unroll
    for (int t = 0; t < 2; ++t){
        f32x16 a;
        #pragma unroll
        for (int g = 0; g < 4; ++g){
            f32x4 bv = *(const f32x4*)(bs + 32 * t + 8 * g + hf4);
            a[4*g+0] = bv[0]; a[4*g+1] = bv[1]; a[4*g+2] = bv[2]; a[4*g+3] = bv[3];
        }
        #pragma unroll
        for (int kc = 0; kc < 4; ++kc){
            f16x8 Af = *(const f16x8*)(wr + t * 2048 + kc * 512);
            f16x8 bB = A0[kc];
            if constexpr (NP >= 2){ bB = bB + A1[kc]; }
            if constexpr (NP >= 3){ bB = bB + A2[kc]; }
            a = MFMA32(Af, bB, a);
        }
        #pragma unroll
        for (int g = 0; g < 4; ++g){
            float o[4];
            if constexpr (ACTI == 0)      tanh4b<false>(a[4*g+0], a[4*g+1], a[4*g+2], a[4*g+3], o);
            else if constexpr (ACTI == 5) tanh4b<true >(a[4*g+0], a[4*g+1], a[4*g+2], a[4*g+3], o);
            else {
                o[0] = act<ACTI>(a[4*g+0]); o[1] = act<ACTI>(a[4*g+1]);
                o[2] = act<ACTI>(a[4*g+2]); o[3] = act<ACTI>(a[4*g+3]);
            }
            pk[t][g] = pack4(o[0], o[1], o[2], o[3]);
        }
    }
    #pragma unroll
    for (int kc = 0; kc < 4; ++kc)
        OUT[kc] = cat8(pk[0][kc], pk[1][kc]);
}

// 1024-thread block (16 waves) + 106KB LDS -> 1 block/CU, 4 waves/SIMD.
__global__ __launch_bounds__(1024, 1) void inr_mfma8_kernel(
    const float* __restrict__ gx, const float* __restrict__ gy,
    const float* __restrict__ gz, const float* __restrict__ gr,
    const float* __restrict__ gnoise,
    const float* __restrict__ W_noise, const float* __restrict__ b_noise,
    const float* __restrict__ W_x, const float* __restrict__ W_y,
    const float* __restrict__ W_z, const float* __restrict__ W_r,
    const float* __restrict__ W1, const float* __restrict__ b1,
    const float* __restrict__ Wg, const float* __restrict__ bg,
    const float* __restrict__ W_out, const float* __restrict__ b_out,
    float* __restrict__ out, int nt, int niter)
{
    // ---- LDS ~106 KB, 1 block (16 waves) per CU -> 4 waves/SIMD ----
    __shared__ __align__(16) f16   wfrag[12][2][4][64][8]; // 96 KB  prescaled W^T A-frags, pi-permuted k
    __shared__ __align__(16) f16   nfrag[2][64][8];        //  2 KB  raw W_noise^T
    __shared__ __align__(16) f16   ofrag[4][64][8];        //  4 KB  -log2e*W_out^T (pi, rows>=3 zero)
    __shared__ __align__(16) float b_s[12][64];            //  3 KB  prescaled biases
    __shared__ __align__(16) float wvs[4][64];             //  1 KB  [0]=-log2e/2*Wx^2, [1]=Wy, [2]=Wz, [3]=Wr
    __shared__ __align__(16) float bns[64];                //  256B  raw b_noise
    __shared__            float bout_s[4];

    const int tid  = threadIdx.x;
    const int lane = tid & 63;
    const int n2   = lane & 31;      // point-in-tile (MFMA col)
    const int hf   = lane >> 5;      // half-wave
    const int hf4  = 4 * hf;

    // ================= PREP: barrier-free direct global->frag (grid=256 -> once per CU) ======
    if (tid < 768){
        int node = tid >> 6, f = tid & 63;
        b_s[node][f] = NSCL[node] * ((node == 0) ? b1[f] : bg[(node - 1) * 64 + f]);
    }
    if (tid < 256){
        int vec = tid >> 6, f = tid & 63;
        float v;
        if      (vec == 0){ float w = W_x[f]; v = (-0.5f * LOG2E) * w * w; }
        else if (vec == 1){ v = W_y[f]; }
        else if (vec == 2){ v = W_z[f]; }
        else              { v = W_r[f]; }
        wvs[vec][f] = v;
    }
    if (tid < 64) bns[tid] = b_noise[tid];
    if (tid < 4)  bout_s[tid] = (tid < 3) ? C_SIG * b_out[tid] : 0.0f;
    if (tid < 128){                                  // nfrag: A[m][k]=W_noise[k][m], k=8h+j
        int t = tid >> 6, ln = tid & 63, m = ln & 31, h = ln >> 5;
        f16x8 v;
        #pragma unroll
        for (int j = 0; j < 8; ++j) v[j] = (f16)(W_noise[(8 * h + j) * 64 + 32 * t + m]);
        *(f16x8*)&nfrag[t][ln][0] = v;
    }
    if (tid < 256){                                  // ofrag: A[m][k]=-log2e*W_out[pi][m] (m<3)
        int kc = tid >> 6, ln = tid & 63, m = ln & 31, h = ln >> 5;
        f16x8 v;
        #pragma unroll
        for (int j = 0; j < 8; ++j){
            int kf = 8 * kc + 32 * (j >> 2) + 4 * h + (j & 3);
            v[j] = (m < 3) ? (f16)(C_SIG * W_out[kf * 3 + m]) : (f16)0.0f;
        }
        *(f16x8*)&ofrag[kc][ln][0] = v;
    }
    // big weights: 1024 threads cover the 512 frag slots twice -> each half does 6 nodes,
    // straight from global (L2-hot), one ds_write_b128 each, NO intermediate barriers
    {
        const int sub = tid & 511;
        const int t = sub >> 8, kc = (sub >> 6) & 3, ln = sub & 63, m = ln & 31, h = ln >> 5;
        int kfo[8];
        #pragma unroll
        for (int j = 0; j < 8; ++j)
            kfo[j] = (8 * kc + 32 * (j >> 2) + 4 * h + (j & 3)) * 64 + 32 * t + m;
        #pragma unroll
        for (int node = tid >> 9; node < 12; node += 2){
            const float* Wsrc = (node == 0) ? W1 : (Wg + (node - 1) * 4096);
            const float  scl  = NSCL[node];
            f16x8 v;
            #pragma unroll
            for (int j = 0; j < 8; ++j) v[j] = (f16)(scl * Wsrc[kfo[j]]);
            *(f16x8*)&wfrag[node][t][kc][ln][0] = v;
        }
    }
    __syncthreads();   // single barrier: all fragments complete

    #define WPTR(NI) (&wfrag[NI][0][0][lane][0])
    #define N1(NI, ACTI, A, OUT)        node32<ACTI,1>(WPTR(NI), &b_s[NI][0], hf4, A, A, A, OUT)
    #define N2(NI, ACTI, A, B, OUT)     node32<ACTI,2>(WPTR(NI), &b_s[NI][0], hf4, A, B, B, OUT)
    #define N3(NI, ACTI, A, B, C, OUT)  node32<ACTI,3>(WPTR(NI), &b_s[NI][0], hf4, A, B, C, OUT)

    const int wvid = tid >> 6;       // wave id 0..15

    // ================= MAIN LOOP: 1 tile (32 pts) per wave per iter =================
    for (int it = 0; it < niter; ++it){
        const int tile = (it * gridDim.x + blockIdx.x) * 16 + wvid;
        if (tile >= nt) break;
        const int myp = tile * 32 + n2;

        // ---- input stage -> ring buffer ra ----
        f16x8 ra[4];
        {
            const float xs = gx[myp], ys = gy[myp], zs = gz[myp], rs = gr[myp];
            const float xs2 = xs * xs;
            f16x8 nb;
            {
                const float4 a4 = *(const float4*)(gnoise + (size_t)myp * 16 + 8 * hf);
                const float4 b4 = *(const float4*)(gnoise + (size_t)myp * 16 + 8 * hf + 4);
                nb = cat8(pack4(a4.x, a4.y, a4.z, a4.w), pack4(b4.x, b4.y, b4.z, b4.w));
            }
            f16x4 pkg[2][4];
            #pragma unroll
            for (int t = 0; t < 2; ++t){
                f32x16 ac;
                #pragma unroll
                for (int i = 0; i < 16; ++i) ac[i] = 0.0f;
                ac = MFMA32(*(const f16x8*)&nfrag[t][lane][0], nb, ac);
                #pragma unroll
                for (int g = 0; g < 4; ++g){
                    const int fb = 32 * t + 8 * g + hf4;
                    const f32x4 wx2 = *(const f32x4*)&wvs[0][fb];   // -log2e/2*Wx^2
                    const f32x4 wyt = *(const f32x4*)&wvs[1][fb];   // Wy (raw)
                    const f32x4 wz  = *(const f32x4*)&wvs[2][fb];
                    const f32x4 wr_ = *(const f32x4*)&wvs[3][fb];
                    const f32x4 bn  = *(const f32x4*)&bns[fb];      // raw b_noise
                    float gv[4];
                    #pragma unroll
                    for (int r = 0; r < 4; ++r){
                        float az = zs * wz[r];
                        float velu = az > 0.0f ? az : (fexp2(az * LOG2E) - 1.0f);
                        float vga = fexp2(xs2 * wx2[r]);
                        float ar = rs * wr_[r];
                        float vsp = fmaxf(ar, 0.0f) + LN2 * flog2(1.0f + fexp2(-LOG2E * fabsf(ar)));
                        // pair-batched Pade tanh: vty = tanh(ys*Wy), vtp = tanh(noise line)
                        float xy = clamp46(ys * wyt[r]);
                        float xt = clamp46(ac[4 * g + r] + bn[r]);
                        float sy = xy * xy, st = xt * xt;
                        float ny = pnum(xy, sy), dy = pden(sy);
                        float np = pnum(xt, st), dp = pden(st);
                        float rp = frcp(dy * dp);
                        float vty = ny * (dp * rp);
                        float vtp = np * (dy * rp);
                        gv[r] = fsin1((velu + vga + vty + vsp + vtp) * C_SIN);
                    }
                    pkg[t][g] = pack4(gv[0], gv[1], gv[2], gv[3]);
                }
            }
            #pragma unroll
            for (int kc = 0; kc < 4; ++kc) ra[kc] = cat8(pkg[0][kc], pkg[1][kc]);
        }

        // ---- graph: 5-buffer ring (h0 + ra/rb/rc/rd), sg merged into ra ----
        f16x8 h0[4], rb[4], rc[4], rd[4];
        N1(0,  0, ra, h0);                 // h0 = tanh(g @ W1 + b1)
        N1(1,  0, h0, ra);                 // h1 = tanh(h0 W)
        N1(2,  1, ra, rb);                 // h2 = elu(h1 W)
        N2(3,  2, rb, h0, rc);             // h3 = softplus((h2+h0) W)
        N3(4,  3, rc, ra, h0, rd);         // h4 = sin((h3+h1+h0) W)
        N2(5,  4, rd, rb, ra);             // h5 = gauss((h4+h2) W)
        N2(6,  5, ra, rc, rb);             // h6 = sigmoid((h5+h3) W)
        N2(7,  0, rb, rd, rc);             // h7 = tanh((h6+h4) W)
        N3(8,  1, rc, ra, h0, rd);         // h8 = elu((h7+h5+h0) W)
        N2(9,  2, rd, rb, ra);             // h9 = softplus((h8+h6) W)
        N2(10, 3, ra, rc, rb);             // h10= sin((h9+h7) W)
        N2(11, 4, rb, rd, rc);             // h11= gauss((h10+h8) W)

        // ---- output: exact hw sigmoid folded into ofrag: out = rcp(1+exp2(om+bout)) ----
        {
            f32x16 om;
            #pragma unroll
            for (int i = 0; i < 16; ++i) om[i] = 0.0f;
            #pragma unroll
            for (int kc = 0; kc < 4; ++kc)
                om = MFMA32(*(const f16x8*)&ofrag[kc][lane][0], rc[kc], om);
            if (hf == 0){
                #pragma unroll
                for (int r = 0; r < 3; ++r)
                    out[(size_t)myp * 3 + r] = frcp(1.0f + fexp2(om[r] + bout_s[r]));
            }
        }
    }
    #undef N1
    #undef N2
    #undef N3
    #undef WPTR
}

extern "C" void kernel_launch(void* const* d_in, const int* in_sizes, int n_in,
                              void* d_out, int out_size, void* d_ws, size_t ws_size,
                              hipStream_t stream)
{
    const float* x       = (const float*)d_in[0];
    const float* y       = (const float*)d_in[1];
    const float* z       = (const float*)d_in[2];
    const float* r       = (const float*)d_in[3];
    const float* noise   = (const float*)d_in[4];
    const float* W_noise = (const float*)d_in[5];
    const float* b_noise = (const float*)d_in[6];
    const float* W_x     = (const float*)d_in[7];
    const float* W_y     = (const float*)d_in[8];
    const float* W_z     = (const float*)d_in[9];
    const float* W_r     = (const float*)d_in[10];
    const float* W1      = (const float*)d_in[11];
    const float* b1      = (const float*)d_in[12];
    const float* Wg      = (const float*)d_in[13];
    const float* bg      = (const float*)d_in[14];
    const float* W_out   = (const float*)d_in[15];
    const float* b_out   = (const float*)d_in[16];
    float* out = (float*)d_out;

    const int n     = in_sizes[0];
    const int nt    = n / 32;                       // 32-pt tiles (8192)
    const int grid  = 256;                          // 1 block per CU; prep once per CU
    const int tiles_per_pass = grid * 16;           // 16 waves x 1 tile = 4096 -> niter=2
    const int niter = (nt + tiles_per_pass - 1) / tiles_per_pass;
    inr_mfma8_kernel<<<dim3(grid), dim3(1024), 0, stream>>>(
        x, y, z, r, noise, W_noise, b_noise, W_x, W_y, W_z, W_r,
        W1, b1, Wg, bg, W_out, b_out, out, nt, niter);
}

// Round 6
// 151.986 us; speedup vs baseline: 1.1498x; 1.1498x over previous
//
#include <hip/hip_runtime.h>

typedef _Float16 f16;
typedef f16  f16x4 __attribute__((ext_vector_type(4)));
typedef f16  f16x8 __attribute__((ext_vector_type(8)));
typedef __fp16 h16x2 __attribute__((ext_vector_type(2)));  // cvt_pkrtz native return type
typedef float f32x4  __attribute__((ext_vector_type(4)));
typedef float f32x16 __attribute__((ext_vector_type(16)));
typedef unsigned int u32;
typedef u32 u32x2 __attribute__((ext_vector_type(2)));
typedef u32 u32x4 __attribute__((ext_vector_type(4)));

#define LOG2E   1.4426950408889634f
#define LN2     0.6931471805599453f
#define C_TANH  2.8853900817779268f    // 2*log2(e)
#define C_SIN   0.15915494309189535f   // 1/(2*pi)
#define C_SIG  -1.4426950408889634f    // -log2(e)
#define C_GAU  -0.7213475204444817f    // -log2(e)/2
#define C_GSQ   0.84932180028802f      // sqrt(log2(e)/2): gauss = exp2(-(s*u)^2)

// per-node arg prescale baked into W,b at prep: acts 0=tanh,1=elu,2=softplus,3=sin,4=gauss,5=sigmoid
// tanh: 2log2e bake; softplus: log2e bake (4-op form); gauss: sqrt(log2e/2) bake (2-op form);
// sigmoid: -log2e bake; sin: 1/2pi bake.
__device__ __constant__ float NSCL[12] = {
    C_TANH, C_TANH, 1.0f, LOG2E, C_SIN, C_GSQ, C_SIG, C_TANH, 1.0f, LOG2E, C_SIN, C_GSQ
};

__device__ __forceinline__ float frcp(float x){ return __builtin_amdgcn_rcpf(x); }
__device__ __forceinline__ float fexp2(float x){ return __builtin_amdgcn_exp2f(x); }
__device__ __forceinline__ float flog2(float x){ return __builtin_amdgcn_logf(x); }
__device__ __forceinline__ float fsin1(float x){ return __builtin_amdgcn_sinf(x); } // arg in revolutions

// ---------- activations on PRESCALED args (see NSCL) ----------
// measured (r5 Pade A/B): plain VALU ~4cy, trans ~8cy effective -> only pure op
// DELETION helps; trading 1 trans for >=2 plain ops is a loss.
template<int A> __device__ __forceinline__ float act(float v){
    if constexpr (A == 0){                       // tanh; v = 2log2e*x        (4 ops)
        float t = fexp2(v);
        return 1.0f - 2.0f * frcp(1.0f + t);
    } else if constexpr (A == 1){                // elu; v raw                (5 ops)
        float e = fexp2(v * LOG2E) - 1.0f;
        return v > 0.0f ? v : e;
    } else if constexpr (A == 2){                // softplus; v = log2e*x     (4 ops, was 7)
        return LN2 * flog2(1.0f + fexp2(v));
    } else if constexpr (A == 3){                // sin; v = x/(2pi)          (1 op)
        return fsin1(v);
    } else if constexpr (A == 4){                // gauss; v = sqrt(log2e/2)x (2 ops, was 3)
        return fexp2(-(v * v));
    } else {                                     // sigmoid; v = -log2e*x     (3 ops)
        return frcp(1.0f + fexp2(v));
    }
}

__device__ __forceinline__ f16x4 pack4(float a, float b, float c, float d){
    u32x2 u;
    u[0] = __builtin_bit_cast(u32, __builtin_amdgcn_cvt_pkrtz(a, b));
    u[1] = __builtin_bit_cast(u32, __builtin_amdgcn_cvt_pkrtz(c, d));
    return __builtin_bit_cast(f16x4, u);
}
__device__ __forceinline__ f16x8 cat8(f16x4 lo, f16x4 hi){
    u32x2 a = __builtin_bit_cast(u32x2, lo), b = __builtin_bit_cast(u32x2, hi);
    u32x4 u; u[0] = a[0]; u[1] = a[1]; u[2] = b[0]; u[3] = b[1];
    return __builtin_bit_cast(f16x8, u);
}

#define MFMA32(a, b, c) __builtin_amdgcn_mfma_f32_32x32x16_f16((a), (b), (c), 0, 0, 0)

// K-permutation pi: k-slot (kc, 8h+j) holds feature 8*kc + 32*(j>>2) + 4*h + (j&3);
// next node's B-frag[kc] = cat(pk[t=0][g=kc], pk[t=1][g=kc]) -- registers only.
//
// SINGLE-tile node (one 32-pt tile per wave): 16-wave workgroup caps the unified
// register budget at 128/wave (64 arch VGPR + 64 AGPR with MFMA) -- dual-tile
// state spilled ~500MB/dispatch (rounds 1-2); single-tile fits with zero scratch.
template<int ACTI, int NP>
__device__ __forceinline__ void node32(const f16* __restrict__ wr,   // &wfrag[ni][0][0][lane][0]
                                       const float* __restrict__ bs, // &b_s[ni][0] (prescaled)
                                       const int hf4,                // 4*(lane>>5)
                                       const f16x8 A0[4], const f16x8 A1[4], const f16x8 A2[4],
                                       f16x8 OUT[4])
{
    f16x4 pk[2][4];
    #pragma unroll
    for (int t = 0; t < 2; ++t){
        f32x16 a;
        #pragma unroll
        for (int g = 0; g < 4; ++g){
            f32x4 bv = *(const f32x4*)(bs + 32 * t + 8 * g + hf4);
            a[4*g+0] = bv[0]; a[4*g+1] = bv[1]; a[4*g+2] = bv[2]; a[4*g+3] = bv[3];
        }
        #pragma unroll
        for (int kc = 0; kc < 4; ++kc){
            f16x8 Af = *(const f16x8*)(wr + t * 2048 + kc * 512);
            f16x8 bB = A0[kc];
            if constexpr (NP >= 2){ bB = bB + A1[kc]; }
            if constexpr (NP >= 3){ bB = bB + A2[kc]; }
            a = MFMA32(Af, bB, a);
        }
        #pragma unroll
        for (int g = 0; g < 4; ++g){
            pk[t][g] = pack4(act<ACTI>(a[4*g+0]), act<ACTI>(a[4*g+1]),
                             act<ACTI>(a[4*g+2]), act<ACTI>(a[4*g+3]));
        }
    }
    #pragma unroll
    for (int kc = 0; kc < 4; ++kc)
        OUT[kc] = cat8(pk[0][kc], pk[1][kc]);
}

// 1024-thread block (16 waves) + 106KB LDS -> 1 block/CU, 4 waves/SIMD.
__global__ __launch_bounds__(1024, 1) void inr_mfma8_kernel(
    const float* __restrict__ gx, const float* __restrict__ gy,
    const float* __restrict__ gz, const float* __restrict__ gr,
    const float* __restrict__ gnoise,
    const float* __restrict__ W_noise, const float* __restrict__ b_noise,
    const float* __restrict__ W_x, const float* __restrict__ W_y,
    const float* __restrict__ W_z, const float* __restrict__ W_r,
    const float* __restrict__ W1, const float* __restrict__ b1,
    const float* __restrict__ Wg, const float* __restrict__ bg,
    const float* __restrict__ W_out, const float* __restrict__ b_out,
    float* __restrict__ out, int nt, int niter)
{
    // ---- LDS ~106 KB, 1 block (16 waves) per CU -> 4 waves/SIMD ----
    __shared__ __align__(16) f16   wfrag[12][2][4][64][8]; // 96 KB  prescaled W^T A-frags, pi-permuted k
    __shared__ __align__(16) f16   nfrag[2][64][8];        //  2 KB  2log2e*W_noise^T
    __shared__ __align__(16) f16   ofrag[4][64][8];        //  4 KB  -log2e*W_out^T (pi, rows>=3 zero)
    __shared__ __align__(16) float b_s[12][64];            //  3 KB  prescaled biases
    __shared__ __align__(16) float wvs[4][64];             //  1 KB  [0]=C_GAU*Wx^2, [1]=2log2e*Wy, [2]=Wz, [3]=log2e*Wr
    __shared__ __align__(16) float bns[64];                //  256B  2log2e*b_noise
    __shared__            float bout_s[4];

    const int tid  = threadIdx.x;
    const int lane = tid & 63;
    const int n2   = lane & 31;      // point-in-tile (MFMA col)
    const int hf   = lane >> 5;      // half-wave
    const int hf4  = 4 * hf;

    // ================= PREP: barrier-free direct global->frag (grid=256 -> once per CU) ======
    if (tid < 768){
        int node = tid >> 6, f = tid & 63;
        b_s[node][f] = NSCL[node] * ((node == 0) ? b1[f] : bg[(node - 1) * 64 + f]);
    }
    if (tid < 256){
        int vec = tid >> 6, f = tid & 63;
        float v;
        if      (vec == 0){ float w = W_x[f]; v = C_GAU * w * w; }
        else if (vec == 1){ v = C_TANH * W_y[f]; }
        else if (vec == 2){ v = W_z[f]; }
        else              { v = LOG2E * W_r[f]; }
        wvs[vec][f] = v;
    }
    if (tid < 64) bns[tid] = C_TANH * b_noise[tid];
    if (tid < 4)  bout_s[tid] = (tid < 3) ? C_SIG * b_out[tid] : 0.0f;
    if (tid < 128){                                  // nfrag: A[m][k]=2log2e*W_noise[k][m], k=8h+j
        int t = tid >> 6, ln = tid & 63, m = ln & 31, h = ln >> 5;
        f16x8 v;
        #pragma unroll
        for (int j = 0; j < 8; ++j) v[j] = (f16)(C_TANH * W_noise[(8 * h + j) * 64 + 32 * t + m]);
        *(f16x8*)&nfrag[t][ln][0] = v;
    }
    if (tid < 256){                                  // ofrag: A[m][k]=-log2e*W_out[pi][m] (m<3)
        int kc = tid >> 6, ln = tid & 63, m = ln & 31, h = ln >> 5;
        f16x8 v;
        #pragma unroll
        for (int j = 0; j < 8; ++j){
            int kf = 8 * kc + 32 * (j >> 2) + 4 * h + (j & 3);
            v[j] = (m < 3) ? (f16)(C_SIG * W_out[kf * 3 + m]) : (f16)0.0f;
        }
        *(f16x8*)&ofrag[kc][ln][0] = v;
    }
    // big weights: 1024 threads cover the 512 frag slots twice -> each half does 6 nodes,
    // straight from global (L2-hot), one ds_write_b128 each, NO intermediate barriers
    {
        const int sub = tid & 511;
        const int t = sub >> 8, kc = (sub >> 6) & 3, ln = sub & 63, m = ln & 31, h = ln >> 5;
        int kfo[8];
        #pragma unroll
        for (int j = 0; j < 8; ++j)
            kfo[j] = (8 * kc + 32 * (j >> 2) + 4 * h + (j & 3)) * 64 + 32 * t + m;
        #pragma unroll
        for (int node = tid >> 9; node < 12; node += 2){
            const float* Wsrc = (node == 0) ? W1 : (Wg + (node - 1) * 4096);
            const float  scl  = NSCL[node];
            f16x8 v;
            #pragma unroll
            for (int j = 0; j < 8; ++j) v[j] = (f16)(scl * Wsrc[kfo[j]]);
            *(f16x8*)&wfrag[node][t][kc][ln][0] = v;
        }
    }
    __syncthreads();   // single barrier: all fragments complete

    #define WPTR(NI) (&wfrag[NI][0][0][lane][0])
    #define N1(NI, ACTI, A, OUT)        node32<ACTI,1>(WPTR(NI), &b_s[NI][0], hf4, A, A, A, OUT)
    #define N2(NI, ACTI, A, B, OUT)     node32<ACTI,2>(WPTR(NI), &b_s[NI][0], hf4, A, B, B, OUT)
    #define N3(NI, ACTI, A, B, C, OUT)  node32<ACTI,3>(WPTR(NI), &b_s[NI][0], hf4, A, B, C, OUT)

    const int wvid = tid >> 6;       // wave id 0..15

    // ================= MAIN LOOP: 1 tile (32 pts) per wave per iter =================
    for (int it = 0; it < niter; ++it){
        const int tile = (it * gridDim.x + blockIdx.x) * 16 + wvid;
        if (tile >= nt) break;
        const int myp = tile * 32 + n2;

        // ---- input stage -> ring buffer ra ----
        f16x8 ra[4];
        {
            const float xs = gx[myp], ys = gy[myp], zs = gz[myp], rs = gr[myp];
            const float xs2 = xs * xs;
            f16x8 nb;
            {
                const float4 a4 = *(const float4*)(gnoise + (size_t)myp * 16 + 8 * hf);
                const float4 b4 = *(const float4*)(gnoise + (size_t)myp * 16 + 8 * hf + 4);
                nb = cat8(pack4(a4.x, a4.y, a4.z, a4.w), pack4(b4.x, b4.y, b4.z, b4.w));
            }
            f16x4 pkg[2][4];
            #pragma unroll
            for (int t = 0; t < 2; ++t){
                f32x16 ac;
                #pragma unroll
                for (int i = 0; i < 16; ++i) ac[i] = 0.0f;
                ac = MFMA32(*(const f16x8*)&nfrag[t][lane][0], nb, ac);
                #pragma unroll
                for (int g = 0; g < 4; ++g){
                    const int fb = 32 * t + 8 * g + hf4;
                    const f32x4 wx2 = *(const f32x4*)&wvs[0][fb];   // C_GAU*Wx^2
                    const f32x4 wyt = *(const f32x4*)&wvs[1][fb];   // 2log2e*Wy
                    const f32x4 wz  = *(const f32x4*)&wvs[2][fb];
                    const f32x4 wr_ = *(const f32x4*)&wvs[3][fb];   // log2e*Wr
                    const f32x4 bn  = *(const f32x4*)&bns[fb];      // 2log2e*b_noise
                    float gv[4];
                    #pragma unroll
                    for (int r = 0; r < 4; ++r){
                        float az = zs * wz[r];
                        float velu = az > 0.0f ? az : (fexp2(az * LOG2E) - 1.0f);
                        float vga = fexp2(xs2 * wx2[r]);
                        float vty = 1.0f - 2.0f * frcp(1.0f + fexp2(ys * wyt[r]));
                        float vsp = LN2 * flog2(1.0f + fexp2(rs * wr_[r]));   // softplus 4-op form
                        float vtp = 1.0f - 2.0f * frcp(1.0f + fexp2(ac[4 * g + r] + bn[r]));
                        gv[r] = fsin1((velu + vga + vty + vsp + vtp) * C_SIN);
                    }
                    pkg[t][g] = pack4(gv[0], gv[1], gv[2], gv[3]);
                }
            }
            #pragma unroll
            for (int kc = 0; kc < 4; ++kc) ra[kc] = cat8(pkg[0][kc], pkg[1][kc]);
        }

        // ---- graph: 5-buffer ring (h0 + ra/rb/rc/rd), sg merged into ra ----
        f16x8 h0[4], rb[4], rc[4], rd[4];
        N1(0,  0, ra, h0);                 // h0 = tanh(g @ W1 + b1)
        N1(1,  0, h0, ra);                 // h1 = tanh(h0 W)
        N1(2,  1, ra, rb);                 // h2 = elu(h1 W)
        N2(3,  2, rb, h0, rc);             // h3 = softplus((h2+h0) W)
        N3(4,  3, rc, ra, h0, rd);         // h4 = sin((h3+h1+h0) W)
        N2(5,  4, rd, rb, ra);             // h5 = gauss((h4+h2) W)
        N2(6,  5, ra, rc, rb);             // h6 = sigmoid((h5+h3) W)
        N2(7,  0, rb, rd, rc);             // h7 = tanh((h6+h4) W)
        N3(8,  1, rc, ra, h0, rd);         // h8 = elu((h7+h5+h0) W)
        N2(9,  2, rd, rb, ra);             // h9 = softplus((h8+h6) W)
        N2(10, 3, ra, rc, rb);             // h10= sin((h9+h7) W)
        N2(11, 4, rb, rd, rc);             // h11= gauss((h10+h8) W)

        // ---- output: exact hw sigmoid folded into ofrag: out = rcp(1+exp2(om+bout)) ----
        {
            f32x16 om;
            #pragma unroll
            for (int i = 0; i < 16; ++i) om[i] = 0.0f;
            #pragma unroll
            for (int kc = 0; kc < 4; ++kc)
                om = MFMA32(*(const f16x8*)&ofrag[kc][lane][0], rc[kc], om);
            if (hf == 0){
                #pragma unroll
                for (int r = 0; r < 3; ++r)
                    out[(size_t)myp * 3 + r] = frcp(1.0f + fexp2(om[r] + bout_s[r]));
            }
        }
    }
    #undef N1
    #undef N2
    #undef N3
    #undef WPTR
}

extern "C" void kernel_launch(void* const* d_in, const int* in_sizes, int n_in,
                              void* d_out, int out_size, void* d_ws, size_t ws_size,
                              hipStream_t stream)
{
    const float* x       = (const float*)d_in[0];
    const float* y       = (const float*)d_in[1];
    const float* z       = (const float*)d_in[2];
    const float* r       = (const float*)d_in[3];
    const float* noise   = (const float*)d_in[4];
    const float* W_noise = (const float*)d_in[5];
    const float* b_noise = (const float*)d_in[6];
    const float* W_x     = (const float*)d_in[7];
    const float* W_y     = (const float*)d_in[8];
    const float* W_z     = (const float*)d_in[9];
    const float* W_r     = (const float*)d_in[10];
    const float* W1      = (const float*)d_in[11];
    const float* b1      = (const float*)d_in[12];
    const float* Wg      = (const float*)d_in[13];
    const float* bg      = (const float*)d_in[14];
    const float* W_out   = (const float*)d_in[15];
    const float* b_out   = (const float*)d_in[16];
    float* out = (float*)d_out;

    const int n     = in_sizes[0];
    const int nt    = n / 32;                       // 32-pt tiles (8192)
    const int grid  = 256;                          // 1 block per CU; prep once per CU
    const int tiles_per_pass = grid * 16;           // 16 waves x 1 tile = 4096 -> niter=2
    const int niter = (nt + tiles_per_pass - 1) / tiles_per_pass;
    inr_mfma8_kernel<<<dim3(grid), dim3(1024), 0, stream>>>(
        x, y, z, r, noise, W_noise, b_noise, W_x, W_y, W_z, W_r,
        W1, b1, Wg, bg, W_out, b_out, out, nt, niter);
}